// Round 9
// baseline (296.813 us; speedup 1.0000x reference)
//
#include <hip/hip_runtime.h>
#include <hip/hip_bf16.h>
#include <stdint.h>

typedef float f32x4 __attribute__((ext_vector_type(4)));
typedef short s16x8 __attribute__((ext_vector_type(8)));

__device__ __forceinline__ float bf2f(unsigned short u) {
    union { unsigned int i; float f; } v; v.i = ((unsigned int)u) << 16; return v.f;
}
__device__ __forceinline__ unsigned short f2bf(float f) {
    union { float f; unsigned int i; } v; v.f = f;
    unsigned int x = v.i;
    return (unsigned short)((x + 0x7fffu + ((x >> 16) & 1u)) >> 16);
}
// unpack packed bf16 pair (little-endian: lo = even feat, hi = odd feat)
__device__ __forceinline__ void bfp(unsigned int u, float& lo, float& hi) {
    union { unsigned int i; float f; } a, b;
    a.i = u << 16; b.i = u & 0xffff0000u;
    lo = a.f; hi = b.f;
}
__device__ __forceinline__ void gload16(const void* g, void* l) {
    __builtin_amdgcn_global_load_lds(
        (const __attribute__((address_space(1))) void*)g,
        (__attribute__((address_space(3))) void*)l, 16, 0, 0);
}

// ---------------- fused weight-prep + degree count ----------------
// blocks [0, CB): count edges into deg (pre-zeroed).
// blocks [CB, ...): weight conversion (Wt rows 0..255 = W^T, 256..271 = W@a, lt = lin_W^T).
__global__ void k_prep(const int* __restrict__ ei, int E, int* __restrict__ deg,
                       int CB,
                       const float* __restrict__ gat_lin,
                       const float* __restrict__ lin_W,
                       const float* __restrict__ att_src,
                       const float* __restrict__ att_dst,
                       unsigned short* __restrict__ Wt,
                       unsigned short* __restrict__ lt) {
    int bid = blockIdx.x;
    if (bid < CB) {
        int e = bid * 256 + threadIdx.x;
        if (e < E) atomicAdd(&deg[ei[E + e]], 1);
        return;
    }
    int idx = (bid - CB) * 256 + threadIdx.x;
    const int T1 = 5 * 65536;            // W^T entries
    const int T2 = T1 + 128 * 256;       // + lt entries
    const int T3 = T2 + 5 * 64 * 256;    // + extra rows
    if (idx < T1) {
        int l = idx >> 16, r = idx & 0xFFFF;
        int nrow = r >> 8, k = r & 255;
        Wt[(size_t)l * 81920 + nrow * 256 + k] =
            f2bf(gat_lin[(size_t)l * 65536 + k * 256 + nrow]);
    } else if (idx < T2) {
        int j = idx - T1;
        int nrow = j >> 8, k = j & 255;
        lt[nrow * 256 + k] = f2bf(lin_W[(size_t)k * 128 + nrow]);
    } else if (idx < T3) {
        int j = idx - T2;
        int l = j >> 14, r = j & 16383;
        int row = r >> 8, k = r & 255;
        float v = 0.f;
        if (row < 16) {
            int head = row & 7;
            const float* a = (row < 8) ? (att_src + l * 256 + head * 32)
                                       : (att_dst + l * 256 + head * 32);
            const float* wr = gat_lin + (size_t)l * 65536 + k * 256 + head * 32;
#pragma unroll
            for (int d = 0; d < 32; ++d) v += wr[d] * a[d];
        }
        Wt[(size_t)l * 81920 + (256 + row) * 256 + k] = f2bf(v);
    }
}

// ---------------- graph build: two-level scan ----------------
__global__ __launch_bounds__(256) void k_bsum(const int* __restrict__ deg,
                                              int* __restrict__ bsum, int n) {
    __shared__ int buf[256];
    int i = blockIdx.x * 256 + threadIdx.x;
    buf[threadIdx.x] = (i < n) ? deg[i] + 1 : 0;
    __syncthreads();
#pragma unroll
    for (int off = 128; off > 0; off >>= 1) {
        if ((int)threadIdx.x < off) buf[threadIdx.x] += buf[threadIdx.x + off];
        __syncthreads();
    }
    if (threadIdx.x == 0) bsum[blockIdx.x] = buf[0];
}

__global__ __launch_bounds__(256) void k_scanb(const int* __restrict__ bsum,
                                               int* __restrict__ boff, int nb) {
    __shared__ int buf[256];
    int t = threadIdx.x;
    int v = (t < nb) ? bsum[t] : 0;
    buf[t] = v;
    __syncthreads();
    for (int off = 1; off < 256; off <<= 1) {
        int add = (t >= off) ? buf[t - off] : 0;
        __syncthreads();
        buf[t] += add;
        __syncthreads();
    }
    if (t < nb) boff[t] = buf[t] - v;   // exclusive
}

__global__ __launch_bounds__(256) void k_emit(const int* __restrict__ deg,
                                              const int* __restrict__ boff,
                                              int* __restrict__ rowptr,
                                              int* __restrict__ wo,
                                              float* __restrict__ dinv, int n) {
    __shared__ int buf[256];
    int i = blockIdx.x * 256 + threadIdx.x;
    int v = (i < n) ? deg[i] + 1 : 0;
    buf[threadIdx.x] = v;
    __syncthreads();
    for (int off = 1; off < 256; off <<= 1) {
        int add = ((int)threadIdx.x >= off) ? buf[threadIdx.x - off] : 0;
        __syncthreads();
        buf[threadIdx.x] += add;
        __syncthreads();
    }
    if (i < n) {
        int excl = boff[blockIdx.x] + buf[threadIdx.x] - v;
        rowptr[i] = excl;
        wo[i] = excl;
        dinv[i] = rsqrtf((float)v);
        if (i == n - 1) rowptr[n] = excl + v;
    }
}

__global__ void k_fill(const int* __restrict__ ei, int E, int n,
                       int* wo, int* srcs) {
    int e = blockIdx.x * blockDim.x + threadIdx.x;
    int EP = E + n;
    if (e >= EP) return;
    int s_, d_;
    if (e < E) { s_ = ei[e]; d_ = ei[E + e]; }
    else       { s_ = d_ = e - E; }
    int pos = atomicAdd(&wo[d_], 1);
    srcs[pos] = s_;
}

// ---------------- GCN (rank-1): wave per node ----------------
__global__ __launch_bounds__(256) void k_h0f(const float* __restrict__ x,
                                             const float* __restrict__ dinv,
                                             const int* __restrict__ rowptr,
                                             const int* __restrict__ srcs,
                                             const float* __restrict__ W0,
                                             const float* __restrict__ b0,
                                             unsigned short* __restrict__ hbf,
                                             int n, int Mpad) {
    int wave = threadIdx.x >> 6, lane = threadIdx.x & 63;
    int node = blockIdx.x * 4 + wave;
    if (node >= Mpad) return;
    size_t base = (size_t)node * 256 + lane * 4;
    if (node >= n) {
        ushort4 z = {0, 0, 0, 0};
        *reinterpret_cast<ushort4*>(hbf + base) = z;
        return;
    }
    int p0 = rowptr[node], p1 = rowptr[node + 1];
    float sum = 0.f;
    for (int p = p0 + lane; p < p1; p += 64) {
        int s = srcs[p];
        sum += x[s] * dinv[s];
    }
#pragma unroll
    for (int m = 1; m < 64; m <<= 1) sum += __shfl_xor(sum, m);
    float sv = sum * dinv[node];
    float4 wv = *reinterpret_cast<const float4*>(W0 + lane * 4);
    float4 bv = *reinterpret_cast<const float4*>(b0 + lane * 4);
    ushort4 o;
    o.x = f2bf(fmaxf(sv * wv.x + bv.x, 0.f));
    o.y = f2bf(fmaxf(sv * wv.y + bv.y, 0.f));
    o.z = f2bf(fmaxf(sv * wv.z + bv.z, 0.f));
    o.w = f2bf(fmaxf(sv * wv.w + bv.w, 0.f));
    *reinterpret_cast<ushort4*>(hbf + base) = o;
}

// ---------------- GraphNorm: stats reduce (bf16 stream) ----------------
__global__ __launch_bounds__(256) void k_gn_reduce(const unsigned short* __restrict__ hbf,
                                                   float* sums, float* sumsq, int n) {
    int f = threadIdx.x;
    float s = 0.f, q = 0.f;
    for (int r = blockIdx.x; r < n; r += gridDim.x) {
        float v = bf2f(hbf[(size_t)r * 256 + f]);
        s += v; q += v * v;
    }
    atomicAdd(&sums[f], s);
    atomicAdd(&sumsq[f], q);
}

// ---------------- GN fold: Wt <- diag(scale)*Wt, rowbias = off@Wt, export (s,o) ----------------
__global__ __launch_bounds__(256) void k_gnfold(const float* __restrict__ st,
                                                const float* __restrict__ w,
                                                const float* __restrict__ b,
                                                const float* __restrict__ ms,
                                                unsigned short* __restrict__ Wt,
                                                float* __restrict__ so,
                                                float* __restrict__ rowbias,
                                                float ninv) {
    __shared__ float red[256];
    int col = blockIdx.x, k = threadIdx.x;
    float mean = st[k] * ninv;
    float m2   = st[256 + k] * ninv;
    float msf  = ms[k];
    float var  = m2 + msf * mean * mean * (msf - 2.0f);
    float sc = w[k] * rsqrtf(var + 1e-5f);
    float of = b[k] - msf * mean * sc;
    size_t idx = (size_t)col * 256 + k;
    float wv = bf2f(Wt[idx]);
    red[k] = of * wv;
    __syncthreads();
#pragma unroll
    for (int off = 128; off > 0; off >>= 1) {
        if (k < off) red[k] += red[k + off];
        __syncthreads();
    }
    if (k == 0) rowbias[col] = red[0];
    Wt[idx] = f2bf(sc * wv);
    if (col == 0) { so[k] = sc; so[256 + k] = of; }
}

// ---------------- MFMA GEMM (single-shot tile): C[64, 64panel] = A[64,256] @ Bt[64,256]^T ----
#define BM 64
__global__ __launch_bounds__(512) void k_gemm_mfma(
    const unsigned short* __restrict__ A,
    const unsigned short* __restrict__ Bt,
    unsigned short* __restrict__ Cb,
    float* __restrict__ Cf,
    float* __restrict__ sbuf,
    float* __restrict__ tbuf,
    const float* __restrict__ bias,
    const float* __restrict__ rowbias,
    int M, int ldc)
{
    __shared__ unsigned short As[64 * 256];        // 32 KB
    __shared__ unsigned short Bs[64 * 256];        // 32 KB
    const int tid = threadIdx.x;
    const int bm = blockIdx.x * BM;
    const int bn = blockIdx.y * 64;
    {   // stage A tile + B panel (64 KB total, 8 x gload16 per thread)
        const char* ga = (const char*)(A + (size_t)bm * 256);
        const char* gb = (const char*)(Bt + (size_t)bn * 256);
        char* la = (char*)As;
        char* lb = (char*)Bs;
#pragma unroll
        for (int i = 0; i < 4; ++i) {
            int o  = (i * 512 + tid) * 16;
            int so = o ^ (((o >> 9) & 7) << 4);
            gload16(ga + so, la + o);
            gload16(gb + so, lb + o);
        }
    }
    __syncthreads();

    const int lane = tid & 63;
    const int w  = tid >> 6;                  // 0..7
    const int wm = (w >> 1) * 16;             // 0,16,32,48
    const int wn = (w & 1) * 32;              // 0,32
    const int r  = lane & 15, kb = lane >> 4;
    const int r4 = (lane >> 4) * 4, cc = lane & 15;
    const char* la = (const char*)As;
    const char* lb = (const char*)Bs;

    f32x4 acc[2] = {};
#pragma unroll
    for (int ks = 0; ks < 8; ++ks) {
        int row = wm + r;
        int c16 = (ks * 4 + kb) ^ (row & 7);
        s16x8 af = *(const s16x8*)(la + row * 512 + c16 * 16);
#pragma unroll
        for (int j = 0; j < 2; ++j) {
            int col = wn + j * 16 + r;
            int d16 = (ks * 4 + kb) ^ (col & 7);
            s16x8 bfr = *(const s16x8*)(lb + col * 512 + d16 * 16);
            acc[j] = __builtin_amdgcn_mfma_f32_16x16x32_bf16(af, bfr, acc[j], 0, 0, 0);
        }
    }
#pragma unroll
    for (int j = 0; j < 2; ++j) {
        int col = bn + wn + j * 16 + cc;
        float rb = rowbias ? rowbias[col] : 0.f;
#pragma unroll
        for (int q = 0; q < 4; ++q) {
            int row = bm + wm + r4 + q;
            float v = acc[j][q] + rb;
            if (Cb) {
                if (col < 256) {
                    Cb[(size_t)row * 256 + col] = f2bf(v);
                } else if (col < 264) {
                    sbuf[(size_t)row * 8 + (col - 256)] = v;
                } else if (col < 272) {
                    tbuf[(size_t)row * 8 + (col - 264)] = v;
                }
            } else if (row < M) {
                Cf[(size_t)row * ldc + col] = v + bias[col];
            }
        }
    }
}

// ------ fused: 2-pass softmax+gather (pass1: true max via slot×head lanes; pass2: dep-free) ------
// Wave = 1 node. Pass 2: lanes 0-31 even edges, 32-63 odd edges; lane owns 8 features.
// Optional so = [scale(256), off(256)]: residual h is GN'd on the fly (GN fold).
__global__ __launch_bounds__(256) void k_fagg(const unsigned short* __restrict__ h1,
                                              const float* __restrict__ sbuf,
                                              const float* __restrict__ tbuf,
                                              const int* __restrict__ rowptr,
                                              const int* __restrict__ srcs,
                                              unsigned short* __restrict__ hbf,
                                              const float* __restrict__ bias,
                                              const float* __restrict__ so, int n) {
    int wave = threadIdx.x >> 6, lane = threadIdx.x & 63;
    int node = blockIdx.x * 4 + wave;
    if (node >= n) return;
    int p0 = rowptr[node], p1 = rowptr[node + 1];

    // ---- pass 1: true per-head max. lane = slot(8) x head(8); coalesced srcs loads.
    int h8 = lane & 7;
    int slot = lane >> 3;
    float tv1 = tbuf[node * 8 + h8];
    float m = -1e30f;
    for (int p = p0 + slot; p < p1; p += 8) {
        int s = srcs[p];
        float e = sbuf[s * 8 + h8] + tv1;
        e = (e > 0.f) ? e : 0.2f * e;
        m = fmaxf(m, e);
    }
    m = fmaxf(m, __shfl_xor(m, 8));
    m = fmaxf(m, __shfl_xor(m, 16));
    m = fmaxf(m, __shfl_xor(m, 32));   // lane L holds max for head L&7

    // ---- pass 2: dependence-free weighted gather
    int hid = lane >> 5;            // half id
    int l5 = lane & 31;
    int fl = l5 * 8;                // feature base (8 feats/lane)
    int head = l5 >> 2;             // 4 lanes per head
    float mh = __shfl(m, head);     // my head's max (lane 0..7 hold heads 0..7)
    float tv = tbuf[node * 8 + head];
    float den = 0.f;
    float a0 = 0.f, a1 = 0.f, a2 = 0.f, a3 = 0.f;
    float a4 = 0.f, a5 = 0.f, a6 = 0.f, a7 = 0.f;
    int q = p0 + hid;
    for (; q + 6 < p1; q += 8) {      // 4 edges per half per iteration
        int s0 = srcs[q], s1 = srcs[q + 2], s2 = srcs[q + 4], s3 = srcs[q + 6];
        float e0 = sbuf[s0 * 8 + head] + tv;
        float e1 = sbuf[s1 * 8 + head] + tv;
        float e2 = sbuf[s2 * 8 + head] + tv;
        float e3 = sbuf[s3 * 8 + head] + tv;
        uint4 v0 = *reinterpret_cast<const uint4*>(h1 + (size_t)s0 * 256 + fl);
        uint4 v1 = *reinterpret_cast<const uint4*>(h1 + (size_t)s1 * 256 + fl);
        uint4 v2 = *reinterpret_cast<const uint4*>(h1 + (size_t)s2 * 256 + fl);
        uint4 v3 = *reinterpret_cast<const uint4*>(h1 + (size_t)s3 * 256 + fl);
        e0 = (e0 > 0.f) ? e0 : 0.2f * e0;
        e1 = (e1 > 0.f) ? e1 : 0.2f * e1;
        e2 = (e2 > 0.f) ? e2 : 0.2f * e2;
        e3 = (e3 > 0.f) ? e3 : 0.2f * e3;
        float w0 = __expf(e0 - mh), w1 = __expf(e1 - mh);
        float w2 = __expf(e2 - mh), w3 = __expf(e3 - mh);
        den += (w0 + w1) + (w2 + w3);
        float fl0, fh0, fl1, fh1, fl2, fh2, fl3, fh3;
        bfp(v0.x, fl0, fh0); bfp(v1.x, fl1, fh1); bfp(v2.x, fl2, fh2); bfp(v3.x, fl3, fh3);
        a0 += (w0 * fl0 + w1 * fl1) + (w2 * fl2 + w3 * fl3);
        a1 += (w0 * fh0 + w1 * fh1) + (w2 * fh2 + w3 * fh3);
        bfp(v0.y, fl0, fh0); bfp(v1.y, fl1, fh1); bfp(v2.y, fl2, fh2); bfp(v3.y, fl3, fh3);
        a2 += (w0 * fl0 + w1 * fl1) + (w2 * fl2 + w3 * fl3);
        a3 += (w0 * fh0 + w1 * fh1) + (w2 * fh2 + w3 * fh3);
        bfp(v0.z, fl0, fh0); bfp(v1.z, fl1, fh1); bfp(v2.z, fl2, fh2); bfp(v3.z, fl3, fh3);
        a4 += (w0 * fl0 + w1 * fl1) + (w2 * fl2 + w3 * fl3);
        a5 += (w0 * fh0 + w1 * fh1) + (w2 * fh2 + w3 * fh3);
        bfp(v0.w, fl0, fh0); bfp(v1.w, fl1, fh1); bfp(v2.w, fl2, fh2); bfp(v3.w, fl3, fh3);
        a6 += (w0 * fl0 + w1 * fl1) + (w2 * fl2 + w3 * fl3);
        a7 += (w0 * fh0 + w1 * fh1) + (w2 * fh2 + w3 * fh3);
    }
    for (; q < p1; q += 2) {
        int s0 = srcs[q];
        float e0 = sbuf[s0 * 8 + head] + tv;
        uint4 v0 = *reinterpret_cast<const uint4*>(h1 + (size_t)s0 * 256 + fl);
        e0 = (e0 > 0.f) ? e0 : 0.2f * e0;
        float w0 = __expf(e0 - mh);
        den += w0;
        float fl0, fh0;
        bfp(v0.x, fl0, fh0); a0 += w0 * fl0; a1 += w0 * fh0;
        bfp(v0.y, fl0, fh0); a2 += w0 * fl0; a3 += w0 * fh0;
        bfp(v0.z, fl0, fh0); a4 += w0 * fl0; a5 += w0 * fh0;
        bfp(v0.w, fl0, fh0); a6 += w0 * fl0; a7 += w0 * fh0;
    }
    // merge halves (same m, plain sums)
    den += __shfl_xor(den, 32);
    a0 += __shfl_xor(a0, 32); a1 += __shfl_xor(a1, 32);
    a2 += __shfl_xor(a2, 32); a3 += __shfl_xor(a3, 32);
    a4 += __shfl_xor(a4, 32); a5 += __shfl_xor(a5, 32);
    a6 += __shfl_xor(a6, 32); a7 += __shfl_xor(a7, 32);
    if (hid) return;     // lanes 0-31 finish the row
    float inv = 1.0f / (den + 1e-16f);
    a0 *= inv; a1 *= inv; a2 *= inv; a3 *= inv;
    a4 *= inv; a5 *= inv; a6 *= inv; a7 *= inv;
    float b_[8] = {0.f, 0.f, 0.f, 0.f, 0.f, 0.f, 0.f, 0.f};
    if (bias) {
        float4 blo = *reinterpret_cast<const float4*>(bias + fl);
        float4 bhi = *reinterpret_cast<const float4*>(bias + fl + 4);
        b_[0] = blo.x; b_[1] = blo.y; b_[2] = blo.z; b_[3] = blo.w;
        b_[4] = bhi.x; b_[5] = bhi.y; b_[6] = bhi.z; b_[7] = bhi.w;
    }
    size_t base = (size_t)node * 256 + fl;
    uint4 hv = *reinterpret_cast<const uint4*>(hbf + base);
    float h_[8];
    bfp(hv.x, h_[0], h_[1]); bfp(hv.y, h_[2], h_[3]);
    bfp(hv.z, h_[4], h_[5]); bfp(hv.w, h_[6], h_[7]);
    if (so) {   // apply GN affine to residual
        float4 s0v = *reinterpret_cast<const float4*>(so + fl);
        float4 s1v = *reinterpret_cast<const float4*>(so + fl + 4);
        float4 o0v = *reinterpret_cast<const float4*>(so + 256 + fl);
        float4 o1v = *reinterpret_cast<const float4*>(so + 256 + fl + 4);
        h_[0] = h_[0] * s0v.x + o0v.x; h_[1] = h_[1] * s0v.y + o0v.y;
        h_[2] = h_[2] * s0v.z + o0v.z; h_[3] = h_[3] * s0v.w + o0v.w;
        h_[4] = h_[4] * s1v.x + o1v.x; h_[5] = h_[5] * s1v.y + o1v.y;
        h_[6] = h_[6] * s1v.z + o1v.z; h_[7] = h_[7] * s1v.w + o1v.w;
    }
    float r0 = h_[0] + fmaxf(a0 + b_[0], 0.f);
    float r1 = h_[1] + fmaxf(a1 + b_[1], 0.f);
    float r2 = h_[2] + fmaxf(a2 + b_[2], 0.f);
    float r3 = h_[3] + fmaxf(a3 + b_[3], 0.f);
    float r4 = h_[4] + fmaxf(a4 + b_[4], 0.f);
    float r5 = h_[5] + fmaxf(a5 + b_[5], 0.f);
    float r6 = h_[6] + fmaxf(a6 + b_[6], 0.f);
    float r7 = h_[7] + fmaxf(a7 + b_[7], 0.f);
    uint4 o;
    o.x = (unsigned int)f2bf(r0) | ((unsigned int)f2bf(r1) << 16);
    o.y = (unsigned int)f2bf(r2) | ((unsigned int)f2bf(r3) << 16);
    o.z = (unsigned int)f2bf(r4) | ((unsigned int)f2bf(r5) << 16);
    o.w = (unsigned int)f2bf(r6) | ((unsigned int)f2bf(r7) << 16);
    *reinterpret_cast<uint4*>(hbf + base) = o;
}

// ---------------- launch ----------------
extern "C" void kernel_launch(void* const* d_in, const int* in_sizes, int n_in,
                              void* d_out, int out_size, void* d_ws, size_t ws_size,
                              hipStream_t stream) {
    const float* x        = (const float*)d_in[0];
    const float* W0       = (const float*)d_in[1];
    const float* b0       = (const float*)d_in[2];
    const float* gat_lin  = (const float*)d_in[3];
    const float* att_src  = (const float*)d_in[4];
    const float* att_dst  = (const float*)d_in[5];
    const float* gat_bias = (const float*)d_in[6];
    const float* gn_w     = (const float*)d_in[7];
    const float* gn_b     = (const float*)d_in[8];
    const float* gn_ms    = (const float*)d_in[9];
    const float* lin_W    = (const float*)d_in[10];
    const float* lin_b    = (const float*)d_in[11];
    const int*   ei       = (const int*)d_in[12];

    const int n  = in_sizes[0];          // 20000
    const int E  = in_sizes[12] / 2;     // 160000
    const int EP = E + n;                // 180000
    const int Mpad = ((n + BM - 1) / BM) * BM;   // 20032
    const int nb = (n + 255) / 256;      // scan blocks (79)

    // workspace layout (16B-aligned chunks)
    char* w = (char*)d_ws;
    unsigned short* hbf = (unsigned short*)w; w += (size_t)Mpad * 256 * 2;
    unsigned short* h1  = (unsigned short*)w; w += (size_t)Mpad * 256 * 2;
    float* sbuf = (float*)w;                  w += (size_t)Mpad * 8 * 4;
    float* tbuf = (float*)w;                  w += (size_t)Mpad * 8 * 4;
    unsigned short* Wt = (unsigned short*)w;  w += (size_t)5 * 320 * 256 * 2;
    unsigned short* lt = (unsigned short*)w;  w += (size_t)128 * 256 * 2;
    float* scaleoff = (float*)w;              w += 1024 * 4;   // 2 groups x (s,o)
    float* rowbias  = (float*)w;              w += 640 * 4;    // 2 groups x 320
    float* gnstat = (float*)w;                w += 1024 * 4;   // zeroed (with deg)
    int* deg    = (int*)w;                    w += (size_t)n * 4;
    float* dinv = (float*)w;                  w += (size_t)n * 4;
    int* rowptr = (int*)w;                    w += ((size_t)(n + 1) * 4 + 15) / 16 * 16;
    int* wo     = (int*)w;                    w += (size_t)n * 4;
    int* bsum   = (int*)w;                    w += ((size_t)nb * 4 + 15) / 16 * 16;
    int* boff   = (int*)w;                    w += ((size_t)nb * 4 + 15) / 16 * 16;
    int* srcs   = (int*)w;                    w += (size_t)EP * 4;

    const int B256 = 256;
    auto cdiv = [](int a, int b) { return (a + b - 1) / b; };

    // zero gnstat + deg in one memset (contiguous)
    hipMemsetAsync(gnstat, 0, 1024 * 4 + (size_t)n * 4, stream);

    // fused weight prep + degree count
    const int CB = cdiv(E, B256);
    const int WPREP = 5 * 65536 + 128 * 256 + 5 * 64 * 256;
    k_prep<<<CB + cdiv(WPREP, B256), B256, 0, stream>>>(
        ei, E, deg, CB, gat_lin, lin_W, att_src, att_dst, Wt, lt);

    // graph build (parallel two-level scan)
    k_bsum<<<nb, 256, 0, stream>>>(deg, bsum, n);
    k_scanb<<<1, 256, 0, stream>>>(bsum, boff, nb);
    k_emit<<<nb, 256, 0, stream>>>(deg, boff, rowptr, wo, dinv, n);
    k_fill<<<cdiv(EP, B256), B256, 0, stream>>>(ei, E, n, wo, srcs);

    // GCN layer (rank-1, wave per node)
    k_h0f<<<cdiv(Mpad, 4), 256, 0, stream>>>(x, dinv, rowptr, srcs, W0, b0, hbf, n, Mpad);

    const float ninv = 1.0f / (float)n;
    const int gx = Mpad / BM;   // 313

    for (int i = 0; i < 5; ++i) {
        const float* rb = nullptr;
        const float* so = nullptr;
        if (i % 3 == 0) {
            int g = i / 3;
            k_gn_reduce<<<256, 256, 0, stream>>>(hbf, gnstat + g * 512,
                                                 gnstat + g * 512 + 256, n);
            k_gnfold<<<320, 256, 0, stream>>>(gnstat + g * 512, gn_w + g * 256,
                                              gn_b + g * 256, gn_ms + g * 256,
                                              Wt + (size_t)i * 81920,
                                              scaleoff + g * 512, rowbias + g * 320, ninv);
            rb = rowbias + g * 320;
            so = scaleoff + g * 512;
        }
        k_gemm_mfma<<<dim3(gx, 5), 512, 0, stream>>>(
            hbf, Wt + (size_t)i * 81920, h1, nullptr, sbuf, tbuf, nullptr, rb,
            n, 256);
        k_fagg<<<cdiv(n, 4), 256, 0, stream>>>(
            h1, sbuf, tbuf, rowptr, srcs, hbf,
            (i % 3 == 0) ? gat_bias + i * 256 : nullptr, so, n);
    }

    // final linear -> d_out (fp32, guarded, +bias), N=128 in 2 panels
    k_gemm_mfma<<<dim3(gx, 2), 512, 0, stream>>>(
        hbf, lt, nullptr, (float*)d_out, nullptr, nullptr, lin_b, nullptr,
        n, 128);
}

// Round 10
// 282.025 us; speedup vs baseline: 1.0524x; 1.0524x over previous
//
#include <hip/hip_runtime.h>
#include <hip/hip_bf16.h>
#include <stdint.h>

typedef float f32x4 __attribute__((ext_vector_type(4)));
typedef short s16x8 __attribute__((ext_vector_type(8)));

__device__ __forceinline__ float bf2f(unsigned short u) {
    union { unsigned int i; float f; } v; v.i = ((unsigned int)u) << 16; return v.f;
}
__device__ __forceinline__ unsigned short f2bf(float f) {
    union { float f; unsigned int i; } v; v.f = f;
    unsigned int x = v.i;
    return (unsigned short)((x + 0x7fffu + ((x >> 16) & 1u)) >> 16);
}
// unpack packed bf16 pair (little-endian: lo = even feat, hi = odd feat)
__device__ __forceinline__ void bfp(unsigned int u, float& lo, float& hi) {
    union { unsigned int i; float f; } a, b;
    a.i = u << 16; b.i = u & 0xffff0000u;
    lo = a.f; hi = b.f;
}
__device__ __forceinline__ void gload16(const void* g, void* l) {
    __builtin_amdgcn_global_load_lds(
        (const __attribute__((address_space(1))) void*)g,
        (__attribute__((address_space(3))) void*)l, 16, 0, 0);
}

// ---------------- fused weight-prep + degree count ----------------
__global__ void k_prep(const int* __restrict__ ei, int E, int* __restrict__ deg,
                       int CB,
                       const float* __restrict__ gat_lin,
                       const float* __restrict__ lin_W,
                       const float* __restrict__ att_src,
                       const float* __restrict__ att_dst,
                       unsigned short* __restrict__ Wt,
                       unsigned short* __restrict__ lt) {
    int bid = blockIdx.x;
    if (bid < CB) {
        int e = bid * 256 + threadIdx.x;
        if (e < E) atomicAdd(&deg[ei[E + e]], 1);
        return;
    }
    int idx = (bid - CB) * 256 + threadIdx.x;
    const int T1 = 5 * 65536;            // W^T entries
    const int T2 = T1 + 128 * 256;       // + lt entries
    const int T3 = T2 + 5 * 64 * 256;    // + extra rows
    if (idx < T1) {
        int l = idx >> 16, r = idx & 0xFFFF;
        int nrow = r >> 8, k = r & 255;
        Wt[(size_t)l * 81920 + nrow * 256 + k] =
            f2bf(gat_lin[(size_t)l * 65536 + k * 256 + nrow]);
    } else if (idx < T2) {
        int j = idx - T1;
        int nrow = j >> 8, k = j & 255;
        lt[nrow * 256 + k] = f2bf(lin_W[(size_t)k * 128 + nrow]);
    } else if (idx < T3) {
        int j = idx - T2;
        int l = j >> 14, r = j & 16383;
        int row = r >> 8, k = r & 255;
        float v = 0.f;
        if (row < 16) {
            int head = row & 7;
            const float* a = (row < 8) ? (att_src + l * 256 + head * 32)
                                       : (att_dst + l * 256 + head * 32);
            const float* wr = gat_lin + (size_t)l * 65536 + k * 256 + head * 32;
#pragma unroll
            for (int d = 0; d < 32; ++d) v += wr[d] * a[d];
        }
        Wt[(size_t)l * 81920 + (256 + row) * 256 + k] = f2bf(v);
    }
}

// ---------------- graph build: two-level scan ----------------
__global__ __launch_bounds__(256) void k_bsum(const int* __restrict__ deg,
                                              int* __restrict__ bsum, int n) {
    __shared__ int buf[256];
    int i = blockIdx.x * 256 + threadIdx.x;
    buf[threadIdx.x] = (i < n) ? deg[i] + 1 : 0;
    __syncthreads();
#pragma unroll
    for (int off = 128; off > 0; off >>= 1) {
        if ((int)threadIdx.x < off) buf[threadIdx.x] += buf[threadIdx.x + off];
        __syncthreads();
    }
    if (threadIdx.x == 0) bsum[blockIdx.x] = buf[0];
}

__global__ __launch_bounds__(256) void k_scanb(const int* __restrict__ bsum,
                                               int* __restrict__ boff, int nb) {
    __shared__ int buf[256];
    int t = threadIdx.x;
    int v = (t < nb) ? bsum[t] : 0;
    buf[t] = v;
    __syncthreads();
    for (int off = 1; off < 256; off <<= 1) {
        int add = (t >= off) ? buf[t - off] : 0;
        __syncthreads();
        buf[t] += add;
        __syncthreads();
    }
    if (t < nb) boff[t] = buf[t] - v;   // exclusive
}

__global__ __launch_bounds__(256) void k_emit(const int* __restrict__ deg,
                                              const int* __restrict__ boff,
                                              int* __restrict__ rowptr,
                                              int* __restrict__ wo,
                                              float* __restrict__ dinv, int n) {
    __shared__ int buf[256];
    int i = blockIdx.x * 256 + threadIdx.x;
    int v = (i < n) ? deg[i] + 1 : 0;
    buf[threadIdx.x] = v;
    __syncthreads();
    for (int off = 1; off < 256; off <<= 1) {
        int add = ((int)threadIdx.x >= off) ? buf[threadIdx.x - off] : 0;
        __syncthreads();
        buf[threadIdx.x] += add;
        __syncthreads();
    }
    if (i < n) {
        int excl = boff[blockIdx.x] + buf[threadIdx.x] - v;
        rowptr[i] = excl;
        wo[i] = excl;
        dinv[i] = rsqrtf((float)v);
        if (i == n - 1) rowptr[n] = excl + v;
    }
}

__global__ void k_fill(const int* __restrict__ ei, int E, int n,
                       int* wo, int* srcs) {
    int e = blockIdx.x * blockDim.x + threadIdx.x;
    int EP = E + n;
    if (e >= EP) return;
    int s_, d_;
    if (e < E) { s_ = ei[e]; d_ = ei[E + e]; }
    else       { s_ = d_ = e - E; }
    int pos = atomicAdd(&wo[d_], 1);
    srcs[pos] = s_;
}

// ---------------- GCN (rank-1): wave per node ----------------
__global__ __launch_bounds__(256) void k_h0f(const float* __restrict__ x,
                                             const float* __restrict__ dinv,
                                             const int* __restrict__ rowptr,
                                             const int* __restrict__ srcs,
                                             const float* __restrict__ W0,
                                             const float* __restrict__ b0,
                                             unsigned short* __restrict__ hbf,
                                             int n, int Mpad) {
    int wave = threadIdx.x >> 6, lane = threadIdx.x & 63;
    int node = blockIdx.x * 4 + wave;
    if (node >= Mpad) return;
    size_t base = (size_t)node * 256 + lane * 4;
    if (node >= n) {
        ushort4 z = {0, 0, 0, 0};
        *reinterpret_cast<ushort4*>(hbf + base) = z;
        return;
    }
    int p0 = rowptr[node], p1 = rowptr[node + 1];
    float sum = 0.f;
    for (int p = p0 + lane; p < p1; p += 64) {
        int s = srcs[p];
        sum += x[s] * dinv[s];
    }
#pragma unroll
    for (int m = 1; m < 64; m <<= 1) sum += __shfl_xor(sum, m);
    float sv = sum * dinv[node];
    float4 wv = *reinterpret_cast<const float4*>(W0 + lane * 4);
    float4 bv = *reinterpret_cast<const float4*>(b0 + lane * 4);
    ushort4 o;
    o.x = f2bf(fmaxf(sv * wv.x + bv.x, 0.f));
    o.y = f2bf(fmaxf(sv * wv.y + bv.y, 0.f));
    o.z = f2bf(fmaxf(sv * wv.z + bv.z, 0.f));
    o.w = f2bf(fmaxf(sv * wv.w + bv.w, 0.f));
    *reinterpret_cast<ushort4*>(hbf + base) = o;
}

// ---------------- GraphNorm: stats reduce (bf16 stream) ----------------
__global__ __launch_bounds__(256) void k_gn_reduce(const unsigned short* __restrict__ hbf,
                                                   float* sums, float* sumsq, int n) {
    int f = threadIdx.x;
    float s = 0.f, q = 0.f;
    for (int r = blockIdx.x; r < n; r += gridDim.x) {
        float v = bf2f(hbf[(size_t)r * 256 + f]);
        s += v; q += v * v;
    }
    atomicAdd(&sums[f], s);
    atomicAdd(&sumsq[f], q);
}

// ---------------- GN fold: Wt <- diag(scale)*Wt, rowbias = off@Wt, export (s,o) ----------------
__global__ __launch_bounds__(256) void k_gnfold(const float* __restrict__ st,
                                                const float* __restrict__ w,
                                                const float* __restrict__ b,
                                                const float* __restrict__ ms,
                                                unsigned short* __restrict__ Wt,
                                                float* __restrict__ so,
                                                float* __restrict__ rowbias,
                                                float ninv) {
    __shared__ float red[256];
    int col = blockIdx.x, k = threadIdx.x;
    float mean = st[k] * ninv;
    float m2   = st[256 + k] * ninv;
    float msf  = ms[k];
    float var  = m2 + msf * mean * mean * (msf - 2.0f);
    float sc = w[k] * rsqrtf(var + 1e-5f);
    float of = b[k] - msf * mean * sc;
    size_t idx = (size_t)col * 256 + k;
    float wv = bf2f(Wt[idx]);
    red[k] = of * wv;
    __syncthreads();
#pragma unroll
    for (int off = 128; off > 0; off >>= 1) {
        if (k < off) red[k] += red[k + off];
        __syncthreads();
    }
    if (k == 0) rowbias[col] = red[0];
    Wt[idx] = f2bf(sc * wv);
    if (col == 0) { so[k] = sc; so[256 + k] = of; }
}

// ---------------- MFMA GEMM (single-shot tile): C[64, 64panel] = A[64,256] @ Bt[64,256]^T ----
#define BM 64
__global__ __launch_bounds__(512) void k_gemm_mfma(
    const unsigned short* __restrict__ A,
    const unsigned short* __restrict__ Bt,
    unsigned short* __restrict__ Cb,
    float* __restrict__ Cf,
    float* __restrict__ sbuf,
    float* __restrict__ tbuf,
    const float* __restrict__ bias,
    const float* __restrict__ rowbias,
    int M, int ldc)
{
    __shared__ unsigned short As[64 * 256];        // 32 KB
    __shared__ unsigned short Bs[64 * 256];        // 32 KB
    const int tid = threadIdx.x;
    const int bm = blockIdx.x * BM;
    const int bn = blockIdx.y * 64;
    {   // stage A tile + B panel (64 KB total, 8 x gload16 per thread)
        const char* ga = (const char*)(A + (size_t)bm * 256);
        const char* gb = (const char*)(Bt + (size_t)bn * 256);
        char* la = (char*)As;
        char* lb = (char*)Bs;
#pragma unroll
        for (int i = 0; i < 4; ++i) {
            int o  = (i * 512 + tid) * 16;
            int so = o ^ (((o >> 9) & 7) << 4);
            gload16(ga + so, la + o);
            gload16(gb + so, lb + o);
        }
    }
    __syncthreads();

    const int lane = tid & 63;
    const int w  = tid >> 6;                  // 0..7
    const int wm = (w >> 1) * 16;             // 0,16,32,48
    const int wn = (w & 1) * 32;              // 0,32
    const int r  = lane & 15, kb = lane >> 4;
    const int r4 = (lane >> 4) * 4, cc = lane & 15;
    const char* la = (const char*)As;
    const char* lb = (const char*)Bs;

    f32x4 acc[2] = {};
#pragma unroll
    for (int ks = 0; ks < 8; ++ks) {
        int row = wm + r;
        int c16 = (ks * 4 + kb) ^ (row & 7);
        s16x8 af = *(const s16x8*)(la + row * 512 + c16 * 16);
#pragma unroll
        for (int j = 0; j < 2; ++j) {
            int col = wn + j * 16 + r;
            int d16 = (ks * 4 + kb) ^ (col & 7);
            s16x8 bfr = *(const s16x8*)(lb + col * 512 + d16 * 16);
            acc[j] = __builtin_amdgcn_mfma_f32_16x16x32_bf16(af, bfr, acc[j], 0, 0, 0);
        }
    }
#pragma unroll
    for (int j = 0; j < 2; ++j) {
        int col = bn + wn + j * 16 + cc;
        float rb = rowbias ? rowbias[col] : 0.f;
#pragma unroll
        for (int q = 0; q < 4; ++q) {
            int row = bm + wm + r4 + q;
            float v = acc[j][q] + rb;
            if (Cb) {
                if (col < 256) {
                    Cb[(size_t)row * 256 + col] = f2bf(v);
                } else if (col < 264) {
                    sbuf[(size_t)row * 8 + (col - 256)] = v;
                } else if (col < 272) {
                    tbuf[(size_t)row * 8 + (col - 264)] = v;
                }
            } else if (row < M) {
                Cf[(size_t)row * ldc + col] = v + bias[col];
            }
        }
    }
}

// ------ fused: single-pass softmax+gather with DEFER-MAX + bias/relu/residual ------
// Wave = 1 node. Lanes 0-31 even edges, 32-63 odd edges; lane owns 8 features.
// Rescale only when group max exceeds m+8 (exp(e-m) bounded by e^8) -> iterations
// are independent in the common path (loads overlap across iterations).
__global__ __launch_bounds__(256) void k_fagg(const unsigned short* __restrict__ h1,
                                              const float* __restrict__ sbuf,
                                              const float* __restrict__ tbuf,
                                              const int* __restrict__ rowptr,
                                              const int* __restrict__ srcs,
                                              unsigned short* __restrict__ hbf,
                                              const float* __restrict__ bias,
                                              const float* __restrict__ so, int n) {
    int wave = threadIdx.x >> 6, lane = threadIdx.x & 63;
    int node = blockIdx.x * 4 + wave;
    if (node >= n) return;
    int p0 = rowptr[node], p1 = rowptr[node + 1];
    int hid = lane >> 5;            // half id
    int l5 = lane & 31;
    int fl = l5 * 8;                // feature base (8 feats/lane)
    int head = l5 >> 2;             // 4 lanes per head
    float tv = tbuf[node * 8 + head];
    float m = -1e30f, den = 0.f;
    float a0 = 0.f, a1 = 0.f, a2 = 0.f, a3 = 0.f;
    float a4 = 0.f, a5 = 0.f, a6 = 0.f, a7 = 0.f;
    int q = p0 + hid;
    for (; q + 2 < p1; q += 4) {      // 2 edges per half per iteration
        int s0 = srcs[q], s1 = srcs[q + 2];
        float e0 = sbuf[s0 * 8 + head] + tv;
        float e1 = sbuf[s1 * 8 + head] + tv;
        uint4 v0 = *reinterpret_cast<const uint4*>(h1 + (size_t)s0 * 256 + fl);
        uint4 v1 = *reinterpret_cast<const uint4*>(h1 + (size_t)s1 * 256 + fl);
        e0 = (e0 > 0.f) ? e0 : 0.2f * e0;
        e1 = (e1 > 0.f) ? e1 : 0.2f * e1;
        float em = fmaxf(e0, e1);
        if (em > m + 8.f) {           // rare rescale
            float sc = __expf(m - em);
            den *= sc;
            a0 *= sc; a1 *= sc; a2 *= sc; a3 *= sc;
            a4 *= sc; a5 *= sc; a6 *= sc; a7 *= sc;
            m = em;
        }
        float w0 = __expf(e0 - m), w1 = __expf(e1 - m);
        den += w0 + w1;
        float f0l, f0h, f1l, f1h;
        bfp(v0.x, f0l, f0h); bfp(v1.x, f1l, f1h);
        a0 += w0 * f0l + w1 * f1l;
        a1 += w0 * f0h + w1 * f1h;
        bfp(v0.y, f0l, f0h); bfp(v1.y, f1l, f1h);
        a2 += w0 * f0l + w1 * f1l;
        a3 += w0 * f0h + w1 * f1h;
        bfp(v0.z, f0l, f0h); bfp(v1.z, f1l, f1h);
        a4 += w0 * f0l + w1 * f1l;
        a5 += w0 * f0h + w1 * f1h;
        bfp(v0.w, f0l, f0h); bfp(v1.w, f1l, f1h);
        a6 += w0 * f0l + w1 * f1l;
        a7 += w0 * f0h + w1 * f1h;
    }
    for (; q < p1; q += 2) {
        int s0 = srcs[q];
        float e0 = sbuf[s0 * 8 + head] + tv;
        uint4 v0 = *reinterpret_cast<const uint4*>(h1 + (size_t)s0 * 256 + fl);
        e0 = (e0 > 0.f) ? e0 : 0.2f * e0;
        if (e0 > m + 8.f) {
            float sc = __expf(m - e0);
            den *= sc;
            a0 *= sc; a1 *= sc; a2 *= sc; a3 *= sc;
            a4 *= sc; a5 *= sc; a6 *= sc; a7 *= sc;
            m = e0;
        }
        float w0 = __expf(e0 - m);
        den += w0;
        float f0l, f0h;
        bfp(v0.x, f0l, f0h); a0 += w0 * f0l; a1 += w0 * f0h;
        bfp(v0.y, f0l, f0h); a2 += w0 * f0l; a3 += w0 * f0h;
        bfp(v0.z, f0l, f0h); a4 += w0 * f0l; a5 += w0 * f0h;
        bfp(v0.w, f0l, f0h); a6 += w0 * f0l; a7 += w0 * f0h;
    }
    // merge the two halves' states (possibly different m)
    float mo = __shfl_xor(m, 32);
    float mm = fmaxf(m, mo);
    float sc = __expf(m - mm);
    den *= sc; den += __shfl_xor(den, 32);
    a0 *= sc; a0 += __shfl_xor(a0, 32);
    a1 *= sc; a1 += __shfl_xor(a1, 32);
    a2 *= sc; a2 += __shfl_xor(a2, 32);
    a3 *= sc; a3 += __shfl_xor(a3, 32);
    a4 *= sc; a4 += __shfl_xor(a4, 32);
    a5 *= sc; a5 += __shfl_xor(a5, 32);
    a6 *= sc; a6 += __shfl_xor(a6, 32);
    a7 *= sc; a7 += __shfl_xor(a7, 32);
    if (hid) return;     // lanes 0-31 finish the row
    float inv = 1.0f / (den + 1e-16f);
    a0 *= inv; a1 *= inv; a2 *= inv; a3 *= inv;
    a4 *= inv; a5 *= inv; a6 *= inv; a7 *= inv;
    float b_[8] = {0.f, 0.f, 0.f, 0.f, 0.f, 0.f, 0.f, 0.f};
    if (bias) {
        float4 blo = *reinterpret_cast<const float4*>(bias + fl);
        float4 bhi = *reinterpret_cast<const float4*>(bias + fl + 4);
        b_[0] = blo.x; b_[1] = blo.y; b_[2] = blo.z; b_[3] = blo.w;
        b_[4] = bhi.x; b_[5] = bhi.y; b_[6] = bhi.z; b_[7] = bhi.w;
    }
    size_t base = (size_t)node * 256 + fl;
    uint4 hv = *reinterpret_cast<const uint4*>(hbf + base);
    float h_[8];
    bfp(hv.x, h_[0], h_[1]); bfp(hv.y, h_[2], h_[3]);
    bfp(hv.z, h_[4], h_[5]); bfp(hv.w, h_[6], h_[7]);
    if (so) {   // apply GN affine to residual
        float4 s0v = *reinterpret_cast<const float4*>(so + fl);
        float4 s1v = *reinterpret_cast<const float4*>(so + fl + 4);
        float4 o0v = *reinterpret_cast<const float4*>(so + 256 + fl);
        float4 o1v = *reinterpret_cast<const float4*>(so + 256 + fl + 4);
        h_[0] = h_[0] * s0v.x + o0v.x; h_[1] = h_[1] * s0v.y + o0v.y;
        h_[2] = h_[2] * s0v.z + o0v.z; h_[3] = h_[3] * s0v.w + o0v.w;
        h_[4] = h_[4] * s1v.x + o1v.x; h_[5] = h_[5] * s1v.y + o1v.y;
        h_[6] = h_[6] * s1v.z + o1v.z; h_[7] = h_[7] * s1v.w + o1v.w;
    }
    float r0 = h_[0] + fmaxf(a0 + b_[0], 0.f);
    float r1 = h_[1] + fmaxf(a1 + b_[1], 0.f);
    float r2 = h_[2] + fmaxf(a2 + b_[2], 0.f);
    float r3 = h_[3] + fmaxf(a3 + b_[3], 0.f);
    float r4 = h_[4] + fmaxf(a4 + b_[4], 0.f);
    float r5 = h_[5] + fmaxf(a5 + b_[5], 0.f);
    float r6 = h_[6] + fmaxf(a6 + b_[6], 0.f);
    float r7 = h_[7] + fmaxf(a7 + b_[7], 0.f);
    uint4 o;
    o.x = (unsigned int)f2bf(r0) | ((unsigned int)f2bf(r1) << 16);
    o.y = (unsigned int)f2bf(r2) | ((unsigned int)f2bf(r3) << 16);
    o.z = (unsigned int)f2bf(r4) | ((unsigned int)f2bf(r5) << 16);
    o.w = (unsigned int)f2bf(r6) | ((unsigned int)f2bf(r7) << 16);
    *reinterpret_cast<uint4*>(hbf + base) = o;
}

// ---------------- launch ----------------
extern "C" void kernel_launch(void* const* d_in, const int* in_sizes, int n_in,
                              void* d_out, int out_size, void* d_ws, size_t ws_size,
                              hipStream_t stream) {
    const float* x        = (const float*)d_in[0];
    const float* W0       = (const float*)d_in[1];
    const float* b0       = (const float*)d_in[2];
    const float* gat_lin  = (const float*)d_in[3];
    const float* att_src  = (const float*)d_in[4];
    const float* att_dst  = (const float*)d_in[5];
    const float* gat_bias = (const float*)d_in[6];
    const float* gn_w     = (const float*)d_in[7];
    const float* gn_b     = (const float*)d_in[8];
    const float* gn_ms    = (const float*)d_in[9];
    const float* lin_W    = (const float*)d_in[10];
    const float* lin_b    = (const float*)d_in[11];
    const int*   ei       = (const int*)d_in[12];

    const int n  = in_sizes[0];          // 20000
    const int E  = in_sizes[12] / 2;     // 160000
    const int EP = E + n;                // 180000
    const int Mpad = ((n + BM - 1) / BM) * BM;   // 20032
    const int nb = (n + 255) / 256;      // scan blocks (79)

    // workspace layout (16B-aligned chunks)
    char* w = (char*)d_ws;
    unsigned short* hbf = (unsigned short*)w; w += (size_t)Mpad * 256 * 2;
    unsigned short* h1  = (unsigned short*)w; w += (size_t)Mpad * 256 * 2;
    float* sbuf = (float*)w;                  w += (size_t)Mpad * 8 * 4;
    float* tbuf = (float*)w;                  w += (size_t)Mpad * 8 * 4;
    unsigned short* Wt = (unsigned short*)w;  w += (size_t)5 * 320 * 256 * 2;
    unsigned short* lt = (unsigned short*)w;  w += (size_t)128 * 256 * 2;
    float* scaleoff = (float*)w;              w += 1024 * 4;   // 2 groups x (s,o)
    float* rowbias  = (float*)w;              w += 640 * 4;    // 2 groups x 320
    float* gnstat = (float*)w;                w += 1024 * 4;   // zeroed (with deg)
    int* deg    = (int*)w;                    w += (size_t)n * 4;
    float* dinv = (float*)w;                  w += (size_t)n * 4;
    int* rowptr = (int*)w;                    w += ((size_t)(n + 1) * 4 + 15) / 16 * 16;
    int* wo     = (int*)w;                    w += (size_t)n * 4;
    int* bsum   = (int*)w;                    w += ((size_t)nb * 4 + 15) / 16 * 16;
    int* boff   = (int*)w;                    w += ((size_t)nb * 4 + 15) / 16 * 16;
    int* srcs   = (int*)w;                    w += (size_t)EP * 4;

    const int B256 = 256;
    auto cdiv = [](int a, int b) { return (a + b - 1) / b; };

    // zero gnstat + deg in one memset (contiguous)
    hipMemsetAsync(gnstat, 0, 1024 * 4 + (size_t)n * 4, stream);

    // fused weight prep + degree count
    const int CB = cdiv(E, B256);
    const int WPREP = 5 * 65536 + 128 * 256 + 5 * 64 * 256;
    k_prep<<<CB + cdiv(WPREP, B256), B256, 0, stream>>>(
        ei, E, deg, CB, gat_lin, lin_W, att_src, att_dst, Wt, lt);

    // graph build (parallel two-level scan)
    k_bsum<<<nb, 256, 0, stream>>>(deg, bsum, n);
    k_scanb<<<1, 256, 0, stream>>>(bsum, boff, nb);
    k_emit<<<nb, 256, 0, stream>>>(deg, boff, rowptr, wo, dinv, n);
    k_fill<<<cdiv(EP, B256), B256, 0, stream>>>(ei, E, n, wo, srcs);

    // GCN layer (rank-1, wave per node)
    k_h0f<<<cdiv(Mpad, 4), 256, 0, stream>>>(x, dinv, rowptr, srcs, W0, b0, hbf, n, Mpad);

    const float ninv = 1.0f / (float)n;
    const int gx = Mpad / BM;   // 313

    for (int i = 0; i < 5; ++i) {
        const float* rb = nullptr;
        const float* so = nullptr;
        if (i % 3 == 0) {
            int g = i / 3;
            k_gn_reduce<<<256, 256, 0, stream>>>(hbf, gnstat + g * 512,
                                                 gnstat + g * 512 + 256, n);
            k_gnfold<<<320, 256, 0, stream>>>(gnstat + g * 512, gn_w + g * 256,
                                              gn_b + g * 256, gn_ms + g * 256,
                                              Wt + (size_t)i * 81920,
                                              scaleoff + g * 512, rowbias + g * 320, ninv);
            rb = rowbias + g * 320;
            so = scaleoff + g * 512;
        }
        k_gemm_mfma<<<dim3(gx, 5), 512, 0, stream>>>(
            hbf, Wt + (size_t)i * 81920, h1, nullptr, sbuf, tbuf, nullptr, rb,
            n, 256);
        k_fagg<<<cdiv(n, 4), 256, 0, stream>>>(
            h1, sbuf, tbuf, rowptr, srcs, hbf,
            (i % 3 == 0) ? gat_bias + i * 256 : nullptr, so, n);
    }

    // final linear -> d_out (fp32, guarded, +bias), N=128 in 2 panels
    k_gemm_mfma<<<dim3(gx, 2), 512, 0, stream>>>(
        hbf, lt, nullptr, (float*)d_out, nullptr, nullptr, lin_b, nullptr,
        n, 128);
}

// Round 11
// 280.262 us; speedup vs baseline: 1.0591x; 1.0063x over previous
//
#include <hip/hip_runtime.h>
#include <hip/hip_bf16.h>
#include <stdint.h>

typedef float f32x4 __attribute__((ext_vector_type(4)));
typedef short s16x8 __attribute__((ext_vector_type(8)));

__device__ __forceinline__ float bf2f(unsigned short u) {
    union { unsigned int i; float f; } v; v.i = ((unsigned int)u) << 16; return v.f;
}
__device__ __forceinline__ unsigned short f2bf(float f) {
    union { float f; unsigned int i; } v; v.f = f;
    unsigned int x = v.i;
    return (unsigned short)((x + 0x7fffu + ((x >> 16) & 1u)) >> 16);
}
// unpack packed bf16 pair (little-endian: lo = even feat, hi = odd feat)
__device__ __forceinline__ void bfp(unsigned int u, float& lo, float& hi) {
    union { unsigned int i; float f; } a, b;
    a.i = u << 16; b.i = u & 0xffff0000u;
    lo = a.f; hi = b.f;
}
__device__ __forceinline__ void gload16(const void* g, void* l) {
    __builtin_amdgcn_global_load_lds(
        (const __attribute__((address_space(1))) void*)g,
        (__attribute__((address_space(3))) void*)l, 16, 0, 0);
}

// ---------------- fused weight-prep + degree count ----------------
__global__ void k_prep(const int* __restrict__ ei, int E, int* __restrict__ deg,
                       int CB,
                       const float* __restrict__ gat_lin,
                       const float* __restrict__ lin_W,
                       const float* __restrict__ att_src,
                       const float* __restrict__ att_dst,
                       unsigned short* __restrict__ Wt,
                       unsigned short* __restrict__ lt) {
    int bid = blockIdx.x;
    if (bid < CB) {
        int e = bid * 256 + threadIdx.x;
        if (e < E) atomicAdd(&deg[ei[E + e]], 1);
        return;
    }
    int idx = (bid - CB) * 256 + threadIdx.x;
    const int T1 = 5 * 65536;            // W^T entries
    const int T2 = T1 + 128 * 256;       // + lt entries
    const int T3 = T2 + 5 * 64 * 256;    // + extra rows
    if (idx < T1) {
        int l = idx >> 16, r = idx & 0xFFFF;
        int nrow = r >> 8, k = r & 255;
        Wt[(size_t)l * 81920 + nrow * 256 + k] =
            f2bf(gat_lin[(size_t)l * 65536 + k * 256 + nrow]);
    } else if (idx < T2) {
        int j = idx - T1;
        int nrow = j >> 8, k = j & 255;
        lt[nrow * 256 + k] = f2bf(lin_W[(size_t)k * 128 + nrow]);
    } else if (idx < T3) {
        int j = idx - T2;
        int l = j >> 14, r = j & 16383;
        int row = r >> 8, k = r & 255;
        float v = 0.f;
        if (row < 16) {
            int head = row & 7;
            const float* a = (row < 8) ? (att_src + l * 256 + head * 32)
                                       : (att_dst + l * 256 + head * 32);
            const float* wr = gat_lin + (size_t)l * 65536 + k * 256 + head * 32;
#pragma unroll
            for (int d = 0; d < 32; ++d) v += wr[d] * a[d];
        }
        Wt[(size_t)l * 81920 + (256 + row) * 256 + k] = f2bf(v);
    }
}

// ---------------- graph build: block sums, then emit with inline prefix ----------------
__global__ __launch_bounds__(256) void k_bsum(const int* __restrict__ deg,
                                              int* __restrict__ bsum, int n) {
    __shared__ int buf[256];
    int i = blockIdx.x * 256 + threadIdx.x;
    buf[threadIdx.x] = (i < n) ? deg[i] + 1 : 0;
    __syncthreads();
#pragma unroll
    for (int off = 128; off > 0; off >>= 1) {
        if ((int)threadIdx.x < off) buf[threadIdx.x] += buf[threadIdx.x + off];
        __syncthreads();
    }
    if (threadIdx.x == 0) bsum[blockIdx.x] = buf[0];
}

// emit: block bid computes prefix over bsum[0..bid) in LDS, then local scan (nb <= 256)
__global__ __launch_bounds__(256) void k_emit(const int* __restrict__ deg,
                                              const int* __restrict__ bsum,
                                              int* __restrict__ rowptr,
                                              int* __restrict__ wo,
                                              float* __restrict__ dinv, int n) {
    __shared__ int buf[256];
    int t = threadIdx.x;
    int bid = blockIdx.x;
    // block offset = sum of bsum[0..bid)
    buf[t] = (t < bid) ? bsum[t] : 0;
    __syncthreads();
#pragma unroll
    for (int off = 128; off > 0; off >>= 1) {
        if (t < off) buf[t] += buf[t + off];
        __syncthreads();
    }
    int boff = buf[0];
    __syncthreads();
    // local inclusive scan of this block's chunk
    int i = bid * 256 + t;
    int v = (i < n) ? deg[i] + 1 : 0;
    buf[t] = v;
    __syncthreads();
    for (int off = 1; off < 256; off <<= 1) {
        int add = (t >= off) ? buf[t - off] : 0;
        __syncthreads();
        buf[t] += add;
        __syncthreads();
    }
    if (i < n) {
        int excl = boff + buf[t] - v;
        rowptr[i] = excl;
        wo[i] = excl;
        dinv[i] = rsqrtf((float)v);
        if (i == n - 1) rowptr[n] = excl + v;
    }
}

__global__ void k_fill(const int* __restrict__ ei, int E, int n,
                       int* wo, int* srcs) {
    int e = blockIdx.x * blockDim.x + threadIdx.x;
    int EP = E + n;
    if (e >= EP) return;
    int s_, d_;
    if (e < E) { s_ = ei[e]; d_ = ei[E + e]; }
    else       { s_ = d_ = e - E; }
    int pos = atomicAdd(&wo[d_], 1);
    srcs[pos] = s_;
}

// ---------------- GCN (rank-1): wave per node ----------------
__global__ __launch_bounds__(256) void k_h0f(const float* __restrict__ x,
                                             const float* __restrict__ dinv,
                                             const int* __restrict__ rowptr,
                                             const int* __restrict__ srcs,
                                             const float* __restrict__ W0,
                                             const float* __restrict__ b0,
                                             unsigned short* __restrict__ hbf,
                                             int n, int Mpad) {
    int wave = threadIdx.x >> 6, lane = threadIdx.x & 63;
    int node = blockIdx.x * 4 + wave;
    if (node >= Mpad) return;
    size_t base = (size_t)node * 256 + lane * 4;
    if (node >= n) {
        ushort4 z = {0, 0, 0, 0};
        *reinterpret_cast<ushort4*>(hbf + base) = z;
        return;
    }
    int p0 = rowptr[node], p1 = rowptr[node + 1];
    float sum = 0.f;
    for (int p = p0 + lane; p < p1; p += 64) {
        int s = srcs[p];
        sum += x[s] * dinv[s];
    }
#pragma unroll
    for (int m = 1; m < 64; m <<= 1) sum += __shfl_xor(sum, m);
    float sv = sum * dinv[node];
    float4 wv = *reinterpret_cast<const float4*>(W0 + lane * 4);
    float4 bv = *reinterpret_cast<const float4*>(b0 + lane * 4);
    ushort4 o;
    o.x = f2bf(fmaxf(sv * wv.x + bv.x, 0.f));
    o.y = f2bf(fmaxf(sv * wv.y + bv.y, 0.f));
    o.z = f2bf(fmaxf(sv * wv.z + bv.z, 0.f));
    o.w = f2bf(fmaxf(sv * wv.w + bv.w, 0.f));
    *reinterpret_cast<ushort4*>(hbf + base) = o;
}

// ---------------- GraphNorm: stats reduce (bf16 stream) ----------------
__global__ __launch_bounds__(256) void k_gn_reduce(const unsigned short* __restrict__ hbf,
                                                   float* sums, float* sumsq, int n) {
    int f = threadIdx.x;
    float s = 0.f, q = 0.f;
    for (int r = blockIdx.x; r < n; r += gridDim.x) {
        float v = bf2f(hbf[(size_t)r * 256 + f]);
        s += v; q += v * v;
    }
    atomicAdd(&sums[f], s);
    atomicAdd(&sumsq[f], q);
}

// ---------------- GN fold: Wt <- diag(scale)*Wt, rowbias = off@Wt, export (s,o) ----------------
__global__ __launch_bounds__(256) void k_gnfold(const float* __restrict__ st,
                                                const float* __restrict__ w,
                                                const float* __restrict__ b,
                                                const float* __restrict__ ms,
                                                unsigned short* __restrict__ Wt,
                                                float* __restrict__ so,
                                                float* __restrict__ rowbias,
                                                float ninv) {
    __shared__ float red[256];
    int col = blockIdx.x, k = threadIdx.x;
    float mean = st[k] * ninv;
    float m2   = st[256 + k] * ninv;
    float msf  = ms[k];
    float var  = m2 + msf * mean * mean * (msf - 2.0f);
    float sc = w[k] * rsqrtf(var + 1e-5f);
    float of = b[k] - msf * mean * sc;
    size_t idx = (size_t)col * 256 + k;
    float wv = bf2f(Wt[idx]);
    red[k] = of * wv;
    __syncthreads();
#pragma unroll
    for (int off = 128; off > 0; off >>= 1) {
        if (k < off) red[k] += red[k + off];
        __syncthreads();
    }
    if (k == 0) rowbias[col] = red[0];
    Wt[idx] = f2bf(sc * wv);
    if (col == 0) { so[k] = sc; so[256 + k] = of; }
}

// ---------------- MFMA GEMM (single-shot tile): C[64, 64panel] = A[64,256] @ Bt[64,256]^T ----
#define BM 64
__global__ __launch_bounds__(512) void k_gemm_mfma(
    const unsigned short* __restrict__ A,
    const unsigned short* __restrict__ Bt,
    unsigned short* __restrict__ Cb,
    float* __restrict__ Cf,
    float* __restrict__ sbuf,
    float* __restrict__ tbuf,
    const float* __restrict__ bias,
    const float* __restrict__ rowbias,
    int M, int ldc)
{
    __shared__ unsigned short As[64 * 256];        // 32 KB
    __shared__ unsigned short Bs[64 * 256];        // 32 KB
    const int tid = threadIdx.x;
    const int bm = blockIdx.x * BM;
    const int bn = blockIdx.y * 64;
    {   // stage A tile + B panel (64 KB total, 8 x gload16 per thread)
        const char* ga = (const char*)(A + (size_t)bm * 256);
        const char* gb = (const char*)(Bt + (size_t)bn * 256);
        char* la = (char*)As;
        char* lb = (char*)Bs;
#pragma unroll
        for (int i = 0; i < 4; ++i) {
            int o  = (i * 512 + tid) * 16;
            int so = o ^ (((o >> 9) & 7) << 4);
            gload16(ga + so, la + o);
            gload16(gb + so, lb + o);
        }
    }
    __syncthreads();

    const int lane = tid & 63;
    const int w  = tid >> 6;                  // 0..7
    const int wm = (w >> 1) * 16;             // 0,16,32,48
    const int wn = (w & 1) * 32;              // 0,32
    const int r  = lane & 15, kb = lane >> 4;
    const int r4 = (lane >> 4) * 4, cc = lane & 15;
    const char* la = (const char*)As;
    const char* lb = (const char*)Bs;

    f32x4 acc[2] = {};
#pragma unroll
    for (int ks = 0; ks < 8; ++ks) {
        int row = wm + r;
        int c16 = (ks * 4 + kb) ^ (row & 7);
        s16x8 af = *(const s16x8*)(la + row * 512 + c16 * 16);
#pragma unroll
        for (int j = 0; j < 2; ++j) {
            int col = wn + j * 16 + r;
            int d16 = (ks * 4 + kb) ^ (col & 7);
            s16x8 bfr = *(const s16x8*)(lb + col * 512 + d16 * 16);
            acc[j] = __builtin_amdgcn_mfma_f32_16x16x32_bf16(af, bfr, acc[j], 0, 0, 0);
        }
    }
#pragma unroll
    for (int j = 0; j < 2; ++j) {
        int col = bn + wn + j * 16 + cc;
        float rb = rowbias ? rowbias[col] : 0.f;
#pragma unroll
        for (int q = 0; q < 4; ++q) {
            int row = bm + wm + r4 + q;
            float v = acc[j][q] + rb;
            if (Cb) {
                if (col < 256) {
                    Cb[(size_t)row * 256 + col] = f2bf(v);
                } else if (col < 264) {
                    sbuf[(size_t)row * 8 + (col - 256)] = v;
                } else if (col < 272) {
                    tbuf[(size_t)row * 8 + (col - 264)] = v;
                }
            } else if (row < M) {
                Cf[(size_t)row * ldc + col] = v + bias[col];
            }
        }
    }
}

// ------ fused: single-pass softmax+gather, DEFER-MAX, 4 edges/half/iter ------
// Wave = 1 node. Lanes 0-31 even edges, 32-63 odd edges; lane owns 8 features.
// Rescale only when group max exceeds m+8 -> common path has no cross-iteration
// serialization; 4 independent gather chains in flight per stream.
__global__ __launch_bounds__(256) void k_fagg(const unsigned short* __restrict__ h1,
                                              const float* __restrict__ sbuf,
                                              const float* __restrict__ tbuf,
                                              const int* __restrict__ rowptr,
                                              const int* __restrict__ srcs,
                                              unsigned short* __restrict__ hbf,
                                              const float* __restrict__ bias,
                                              const float* __restrict__ so, int n) {
    int wave = threadIdx.x >> 6, lane = threadIdx.x & 63;
    int node = blockIdx.x * 4 + wave;
    if (node >= n) return;
    int p0 = rowptr[node], p1 = rowptr[node + 1];
    int hid = lane >> 5;            // half id
    int l5 = lane & 31;
    int fl = l5 * 8;                // feature base (8 feats/lane)
    int head = l5 >> 2;             // 4 lanes per head
    float tv = tbuf[node * 8 + head];
    float m = -1e30f, den = 0.f;
    float a0 = 0.f, a1 = 0.f, a2 = 0.f, a3 = 0.f;
    float a4 = 0.f, a5 = 0.f, a6 = 0.f, a7 = 0.f;
    int q = p0 + hid;
    for (; q + 6 < p1; q += 8) {      // 4 edges per half per iteration
        int s0 = srcs[q], s1 = srcs[q + 2], s2 = srcs[q + 4], s3 = srcs[q + 6];
        float e0 = sbuf[s0 * 8 + head] + tv;
        float e1 = sbuf[s1 * 8 + head] + tv;
        float e2 = sbuf[s2 * 8 + head] + tv;
        float e3 = sbuf[s3 * 8 + head] + tv;
        uint4 v0 = *reinterpret_cast<const uint4*>(h1 + (size_t)s0 * 256 + fl);
        uint4 v1 = *reinterpret_cast<const uint4*>(h1 + (size_t)s1 * 256 + fl);
        uint4 v2 = *reinterpret_cast<const uint4*>(h1 + (size_t)s2 * 256 + fl);
        uint4 v3 = *reinterpret_cast<const uint4*>(h1 + (size_t)s3 * 256 + fl);
        e0 = (e0 > 0.f) ? e0 : 0.2f * e0;
        e1 = (e1 > 0.f) ? e1 : 0.2f * e1;
        e2 = (e2 > 0.f) ? e2 : 0.2f * e2;
        e3 = (e3 > 0.f) ? e3 : 0.2f * e3;
        float em = fmaxf(fmaxf(e0, e1), fmaxf(e2, e3));
        if (em > m + 8.f) {           // rare rescale
            float sc = __expf(m - em);
            den *= sc;
            a0 *= sc; a1 *= sc; a2 *= sc; a3 *= sc;
            a4 *= sc; a5 *= sc; a6 *= sc; a7 *= sc;
            m = em;
        }
        float w0 = __expf(e0 - m), w1 = __expf(e1 - m);
        float w2 = __expf(e2 - m), w3 = __expf(e3 - m);
        den += (w0 + w1) + (w2 + w3);
        float fl0, fh0, fl1, fh1, fl2, fh2, fl3, fh3;
        bfp(v0.x, fl0, fh0); bfp(v1.x, fl1, fh1); bfp(v2.x, fl2, fh2); bfp(v3.x, fl3, fh3);
        a0 += (w0 * fl0 + w1 * fl1) + (w2 * fl2 + w3 * fl3);
        a1 += (w0 * fh0 + w1 * fh1) + (w2 * fh2 + w3 * fh3);
        bfp(v0.y, fl0, fh0); bfp(v1.y, fl1, fh1); bfp(v2.y, fl2, fh2); bfp(v3.y, fl3, fh3);
        a2 += (w0 * fl0 + w1 * fl1) + (w2 * fl2 + w3 * fl3);
        a3 += (w0 * fh0 + w1 * fh1) + (w2 * fh2 + w3 * fh3);
        bfp(v0.z, fl0, fh0); bfp(v1.z, fl1, fh1); bfp(v2.z, fl2, fh2); bfp(v3.z, fl3, fh3);
        a4 += (w0 * fl0 + w1 * fl1) + (w2 * fl2 + w3 * fl3);
        a5 += (w0 * fh0 + w1 * fh1) + (w2 * fh2 + w3 * fh3);
        bfp(v0.w, fl0, fh0); bfp(v1.w, fl1, fh1); bfp(v2.w, fl2, fh2); bfp(v3.w, fl3, fh3);
        a6 += (w0 * fl0 + w1 * fl1) + (w2 * fl2 + w3 * fl3);
        a7 += (w0 * fh0 + w1 * fh1) + (w2 * fh2 + w3 * fh3);
    }
    for (; q < p1; q += 2) {
        int s0 = srcs[q];
        float e0 = sbuf[s0 * 8 + head] + tv;
        uint4 v0 = *reinterpret_cast<const uint4*>(h1 + (size_t)s0 * 256 + fl);
        e0 = (e0 > 0.f) ? e0 : 0.2f * e0;
        if (e0 > m + 8.f) {
            float sc = __expf(m - e0);
            den *= sc;
            a0 *= sc; a1 *= sc; a2 *= sc; a3 *= sc;
            a4 *= sc; a5 *= sc; a6 *= sc; a7 *= sc;
            m = e0;
        }
        float w0 = __expf(e0 - m);
        den += w0;
        float f0l, f0h;
        bfp(v0.x, f0l, f0h); a0 += w0 * f0l; a1 += w0 * f0h;
        bfp(v0.y, f0l, f0h); a2 += w0 * f0l; a3 += w0 * f0h;
        bfp(v0.z, f0l, f0h); a4 += w0 * f0l; a5 += w0 * f0h;
        bfp(v0.w, f0l, f0h); a6 += w0 * f0l; a7 += w0 * f0h;
    }
    // merge the two halves' states (possibly different m)
    float mo = __shfl_xor(m, 32);
    float mm = fmaxf(m, mo);
    float sc = __expf(m - mm);
    den *= sc; den += __shfl_xor(den, 32);
    a0 *= sc; a0 += __shfl_xor(a0, 32);
    a1 *= sc; a1 += __shfl_xor(a1, 32);
    a2 *= sc; a2 += __shfl_xor(a2, 32);
    a3 *= sc; a3 += __shfl_xor(a3, 32);
    a4 *= sc; a4 += __shfl_xor(a4, 32);
    a5 *= sc; a5 += __shfl_xor(a5, 32);
    a6 *= sc; a6 += __shfl_xor(a6, 32);
    a7 *= sc; a7 += __shfl_xor(a7, 32);
    if (hid) return;     // lanes 0-31 finish the row
    float inv = 1.0f / (den + 1e-16f);
    a0 *= inv; a1 *= inv; a2 *= inv; a3 *= inv;
    a4 *= inv; a5 *= inv; a6 *= inv; a7 *= inv;
    float b_[8] = {0.f, 0.f, 0.f, 0.f, 0.f, 0.f, 0.f, 0.f};
    if (bias) {
        float4 blo = *reinterpret_cast<const float4*>(bias + fl);
        float4 bhi = *reinterpret_cast<const float4*>(bias + fl + 4);
        b_[0] = blo.x; b_[1] = blo.y; b_[2] = blo.z; b_[3] = blo.w;
        b_[4] = bhi.x; b_[5] = bhi.y; b_[6] = bhi.z; b_[7] = bhi.w;
    }
    size_t base = (size_t)node * 256 + fl;
    uint4 hv = *reinterpret_cast<const uint4*>(hbf + base);
    float h_[8];
    bfp(hv.x, h_[0], h_[1]); bfp(hv.y, h_[2], h_[3]);
    bfp(hv.z, h_[4], h_[5]); bfp(hv.w, h_[6], h_[7]);
    if (so) {   // apply GN affine to residual
        float4 s0v = *reinterpret_cast<const float4*>(so + fl);
        float4 s1v = *reinterpret_cast<const float4*>(so + fl + 4);
        float4 o0v = *reinterpret_cast<const float4*>(so + 256 + fl);
        float4 o1v = *reinterpret_cast<const float4*>(so + 256 + fl + 4);
        h_[0] = h_[0] * s0v.x + o0v.x; h_[1] = h_[1] * s0v.y + o0v.y;
        h_[2] = h_[2] * s0v.z + o0v.z; h_[3] = h_[3] * s0v.w + o0v.w;
        h_[4] = h_[4] * s1v.x + o1v.x; h_[5] = h_[5] * s1v.y + o1v.y;
        h_[6] = h_[6] * s1v.z + o1v.z; h_[7] = h_[7] * s1v.w + o1v.w;
    }
    float r0 = h_[0] + fmaxf(a0 + b_[0], 0.f);
    float r1 = h_[1] + fmaxf(a1 + b_[1], 0.f);
    float r2 = h_[2] + fmaxf(a2 + b_[2], 0.f);
    float r3 = h_[3] + fmaxf(a3 + b_[3], 0.f);
    float r4 = h_[4] + fmaxf(a4 + b_[4], 0.f);
    float r5 = h_[5] + fmaxf(a5 + b_[5], 0.f);
    float r6 = h_[6] + fmaxf(a6 + b_[6], 0.f);
    float r7 = h_[7] + fmaxf(a7 + b_[7], 0.f);
    uint4 o;
    o.x = (unsigned int)f2bf(r0) | ((unsigned int)f2bf(r1) << 16);
    o.y = (unsigned int)f2bf(r2) | ((unsigned int)f2bf(r3) << 16);
    o.z = (unsigned int)f2bf(r4) | ((unsigned int)f2bf(r5) << 16);
    o.w = (unsigned int)f2bf(r6) | ((unsigned int)f2bf(r7) << 16);
    *reinterpret_cast<uint4*>(hbf + base) = o;
}

// ---------------- launch ----------------
extern "C" void kernel_launch(void* const* d_in, const int* in_sizes, int n_in,
                              void* d_out, int out_size, void* d_ws, size_t ws_size,
                              hipStream_t stream) {
    const float* x        = (const float*)d_in[0];
    const float* W0       = (const float*)d_in[1];
    const float* b0       = (const float*)d_in[2];
    const float* gat_lin  = (const float*)d_in[3];
    const float* att_src  = (const float*)d_in[4];
    const float* att_dst  = (const float*)d_in[5];
    const float* gat_bias = (const float*)d_in[6];
    const float* gn_w     = (const float*)d_in[7];
    const float* gn_b     = (const float*)d_in[8];
    const float* gn_ms    = (const float*)d_in[9];
    const float* lin_W    = (const float*)d_in[10];
    const float* lin_b    = (const float*)d_in[11];
    const int*   ei       = (const int*)d_in[12];

    const int n  = in_sizes[0];          // 20000
    const int E  = in_sizes[12] / 2;     // 160000
    const int EP = E + n;                // 180000
    const int Mpad = ((n + BM - 1) / BM) * BM;   // 20032
    const int nb = (n + 255) / 256;      // scan blocks (79)

    // workspace layout (16B-aligned chunks)
    char* w = (char*)d_ws;
    unsigned short* hbf = (unsigned short*)w; w += (size_t)Mpad * 256 * 2;
    unsigned short* h1  = (unsigned short*)w; w += (size_t)Mpad * 256 * 2;
    float* sbuf = (float*)w;                  w += (size_t)Mpad * 8 * 4;
    float* tbuf = (float*)w;                  w += (size_t)Mpad * 8 * 4;
    unsigned short* Wt = (unsigned short*)w;  w += (size_t)5 * 320 * 256 * 2;
    unsigned short* lt = (unsigned short*)w;  w += (size_t)128 * 256 * 2;
    float* scaleoff = (float*)w;              w += 1024 * 4;   // 2 groups x (s,o)
    float* rowbias  = (float*)w;              w += 640 * 4;    // 2 groups x 320
    float* gnstat = (float*)w;                w += 1024 * 4;   // zeroed (with deg)
    int* deg    = (int*)w;                    w += (size_t)n * 4;
    float* dinv = (float*)w;                  w += (size_t)n * 4;
    int* rowptr = (int*)w;                    w += ((size_t)(n + 1) * 4 + 15) / 16 * 16;
    int* wo     = (int*)w;                    w += (size_t)n * 4;
    int* bsum   = (int*)w;                    w += ((size_t)nb * 4 + 15) / 16 * 16;
    int* srcs   = (int*)w;                    w += (size_t)EP * 4;

    const int B256 = 256;
    auto cdiv = [](int a, int b) { return (a + b - 1) / b; };

    // zero gnstat + deg in one memset (contiguous)
    hipMemsetAsync(gnstat, 0, 1024 * 4 + (size_t)n * 4, stream);

    // fused weight prep + degree count
    const int CB = cdiv(E, B256);
    const int WPREP = 5 * 65536 + 128 * 256 + 5 * 64 * 256;
    k_prep<<<CB + cdiv(WPREP, B256), B256, 0, stream>>>(
        ei, E, deg, CB, gat_lin, lin_W, att_src, att_dst, Wt, lt);

    // graph build (bsum -> emit-with-inline-prefix -> fill)
    k_bsum<<<nb, 256, 0, stream>>>(deg, bsum, n);
    k_emit<<<nb, 256, 0, stream>>>(deg, bsum, rowptr, wo, dinv, n);
    k_fill<<<cdiv(EP, B256), B256, 0, stream>>>(ei, E, n, wo, srcs);

    // GCN layer (rank-1, wave per node)
    k_h0f<<<cdiv(Mpad, 4), 256, 0, stream>>>(x, dinv, rowptr, srcs, W0, b0, hbf, n, Mpad);

    const float ninv = 1.0f / (float)n;
    const int gx = Mpad / BM;   // 313

    for (int i = 0; i < 5; ++i) {
        const float* rb = nullptr;
        const float* so = nullptr;
        if (i % 3 == 0) {
            int g = i / 3;
            k_gn_reduce<<<256, 256, 0, stream>>>(hbf, gnstat + g * 512,
                                                 gnstat + g * 512 + 256, n);
            k_gnfold<<<320, 256, 0, stream>>>(gnstat + g * 512, gn_w + g * 256,
                                              gn_b + g * 256, gn_ms + g * 256,
                                              Wt + (size_t)i * 81920,
                                              scaleoff + g * 512, rowbias + g * 320, ninv);
            rb = rowbias + g * 320;
            so = scaleoff + g * 512;
        }
        k_gemm_mfma<<<dim3(gx, 5), 512, 0, stream>>>(
            hbf, Wt + (size_t)i * 81920, h1, nullptr, sbuf, tbuf, nullptr, rb,
            n, 256);
        k_fagg<<<cdiv(n, 4), 256, 0, stream>>>(
            h1, sbuf, tbuf, rowptr, srcs, hbf,
            (i % 3 == 0) ? gat_bias + i * 256 : nullptr, so, n);
    }

    // final linear -> d_out (fp32, guarded, +bias), N=128 in 2 panels
    k_gemm_mfma<<<dim3(gx, 2), 512, 0, stream>>>(
        hbf, lt, nullptr, (float*)d_out, nullptr, nullptr, lin_b, nullptr,
        n, 128);
}